// Round 4
// baseline (140.182 us; speedup 1.0000x reference)
//
#include <hip/hip_runtime.h>
#include <hip/hip_bf16.h>
#include <stdint.h>

typedef __bf16 bf16;
typedef bf16 bf16x8 __attribute__((ext_vector_type(8)));
typedef float f32x4 __attribute__((ext_vector_type(4)));
typedef float f32x16 __attribute__((ext_vector_type(16)));

#define AS1 __attribute__((address_space(1)))
#define AS3 __attribute__((address_space(3)))

__device__ __forceinline__ void async_copy16(const void* g, void* l) {
    __builtin_amdgcn_global_load_lds((const AS1 uint32_t*)(g),
                                     (AS3 uint32_t*)(l), 16, 0, 0);
}

// ---------------- tiny prep kernels ----------------

// s[b,c] = style[b,:] . style_w[c,:] + style_b[c]; block 0 zeroes DMA guard.
__global__ void k_style(const float* __restrict__ style, const float* __restrict__ sw,
                        const float* __restrict__ sbias, float* __restrict__ s_out,
                        float* __restrict__ guard) {
    if (blockIdx.x == 0) {
#pragma unroll
        for (int j = 0; j < 4; ++j) guard[threadIdx.x + 256 * j] = 0.f;
    }
    int gw = (blockIdx.x * blockDim.x + threadIdx.x) >> 6;
    int lane = threadIdx.x & 63;
    if (gw >= 512) return;
    int b = gw >> 7, c = gw & 127;
    const float* st = style + b * 512;
    const float* wr = sw + c * 512;
    float a = 0.f;
#pragma unroll
    for (int j = 0; j < 8; ++j) a += st[lane + 64 * j] * wr[lane + 64 * j];
    for (int off = 32; off > 0; off >>= 1) a += __shfl_down(a, off, 64);
    if (lane == 0) s_out[gw] = a + sbias[c];
}

// sig_inv[b,o] = rsqrt( sum_i (sum_tap W[o,i,tap]^2) * s[b,i]^2 + 1e-8 )
__global__ void k_sig(const float* __restrict__ weight, const float* __restrict__ s,
                      float* __restrict__ sig) {
    int gw = (blockIdx.x * blockDim.x + threadIdx.x) >> 6;
    int lane = threadIdx.x & 63;
    if (gw >= 512) return;
    int b = gw >> 7, o = gw & 127;
    float a = 0.f;
#pragma unroll
    for (int j = 0; j < 2; ++j) {
        int i = lane + 64 * j;
        const float* wr = weight + ((size_t)o * 128 + i) * 9;
        float wsq = 0.f;
#pragma unroll
        for (int t = 0; t < 9; ++t) wsq += wr[t] * wr[t];
        float sv = s[b * 128 + i];
        a += wsq * sv * sv;
    }
    for (int off = 32; off > 0; off >>= 1) a += __shfl_down(a, off, 64);
    if (lane == 0) sig[gw] = rsqrtf(a + 1e-8f);
}

// repack weight fp32 [co][ci][9] -> bf16 wt[chunk8][tap9][g2][co128][8ci]
__global__ void k_wt(const float* __restrict__ weight, bf16* __restrict__ wt) {
    int i = blockIdx.x * 256 + threadIdx.x;
    if (i >= 147456) return;
    int j = i & 7;
    int co = (i >> 3) & 127;
    int g = (i >> 10) & 1;
    int tap = (i >> 11) % 9;
    int chunk = (i >> 11) / 9;
    int ci = chunk * 16 + g * 8 + j;
    wt[i] = (bf16)weight[((size_t)co * 128 + ci) * 9 + tap];
}

// x fp32 [b][ci][hwt] * s[b][ci] -> bf16 xt[b][g=ci>>3][e=hwt][8ci]
__global__ void k_xt(const float* __restrict__ x, const float* __restrict__ s,
                     bf16* __restrict__ xt) {
    int E = blockIdx.x * 256 + threadIdx.x;   // 0..262143
    int b = E >> 16, e = E & 65535;
    const float* xb = x + (size_t)b * 8388608 + e;
    const float* sb = s + b * 128;
#pragma unroll 4
    for (int g = 0; g < 16; ++g) {
        bf16x8 v;
#pragma unroll
        for (int j = 0; j < 8; ++j)
            v[j] = (bf16)(xb[(size_t)(g * 8 + j) * 65536] * sb[g * 8 + j]);
        *(bf16x8*)(xt + ((((size_t)b * 16 + g) << 16) + e) * 8) = v;
    }
}

// ---------------- main MFMA conv kernel ----------------
// grid (4 wblk, 64 h, 4 b); block 256 = 4 waves; tile 128co x 256elem (16w x 16t)
// Round-0 DMA structure + T4 counted-vmcnt pipeline:
//   stage(c+1): exactly 7 global_load_lds per wave (dummy-padded uniform),
//   s_waitcnt vmcnt(7)  -> my S(c) landed, S(c+1) stays in flight,
//   s_barrier           -> everyone's S(c) landed,
//   compute(c),
//   s_barrier           -> all readers of buf[c&1] done before it is re-staged.
// This removes the full vmcnt(0) drain __syncthreads imposed each chunk.
__global__ __launch_bounds__(256, 2) void conv_main(
    const bf16* __restrict__ xt, const bf16* __restrict__ wt,
    const float* __restrict__ sig_inv, const float* __restrict__ npar,
    const float* __restrict__ bpar, const float* __restrict__ noise,
    const bf16* __restrict__ guard, float* __restrict__ out) {
    __shared__ bf16 Xl[2][1728 * 8];   // 2 x 27648 B  [dh3][g2][e288][8ci]
    __shared__ bf16 Xd[64 * 8];        // 1 KB dummy sink for DMA padding

    const int tid = threadIdx.x;
    const int lane = tid & 63;
    const int l31 = lane & 31, lhi = lane >> 5;
    const int wm = (tid >> 6) & 1, wn = tid >> 7;
    const int w0 = blockIdx.x * 16;
    const int h = blockIdx.y;
    const int b = blockIdx.z;
    const size_t bHW = (size_t)b * 65536;

    // stage one X chunk: 1728 real cells + 64 dummy cells so EVERY wave issues
    // exactly 7 DMAs (uniform vmcnt literal). Halo/dummy lanes read the zero
    // guard (in-bounds). LDS dst of global_load_lds is wave-uniform base +
    // lane*16; the dummy redirect happens on a whole-wave boundary (it=6,
    // wave 3).
    auto stage = [&](int chunk, bf16* buf) {
#pragma unroll
        for (int it = 0; it < 7; ++it) {
            int u = it * 256 + tid;
            bool real = u < 1728;
            int ur = real ? u : 0;
            int dh = ur / 576;
            int rem = ur - dh * 576;
            int g = rem / 288;
            int e = rem - g * 288;
            int ha = h - 1 + dh;
            int wa = w0 - 1 + (e >> 4);
            bool ok = real & ((unsigned)ha < 64u) & ((unsigned)wa < 64u);
            int E = (ha * 64 + wa) * 16 + (e & 15);
            const bf16* gsrc = ok
                ? xt + ((((size_t)b * 16 + chunk * 2 + g) << 16) + E) * 8
                : guard;
            bf16* dst = real ? &buf[u * 8] : &Xd[(u - 1728) * 8];
            async_copy16(gsrc, dst);
        }
    };

    f32x16 acc[2][4] = {};

    // prefetch epilogue noise FIRST so it retires before the staging DMAs
    // (vmcnt retires in issue order; keeps the vmcnt(7) literal exact).
    const size_t ebase = bHW + (size_t)h * 1024 + w0 * 16 + wn * 128;
    float ns[4];
#pragma unroll
    for (int nf = 0; nf < 4; ++nf) ns[nf] = noise[ebase + nf * 32 + l31];

    stage(0, Xl[0]);

    for (int chunk = 0; chunk < 8; ++chunk) {
        if (chunk < 7) {
            stage(chunk + 1, Xl[(chunk + 1) & 1]);   // 7 DMAs/wave in flight
            asm volatile("s_waitcnt vmcnt(7)" ::: "memory");
        } else {
            asm volatile("s_waitcnt vmcnt(0)" ::: "memory");
        }
        __builtin_amdgcn_s_barrier();                // S(chunk) visible to all
        __builtin_amdgcn_sched_barrier(0);
        const bf16* Xb = Xl[chunk & 1];

#pragma unroll
        for (int tap = 0; tap < 9; ++tap) {
            const int dh = tap / 3, dw = tap % 3;
            const bf16* wg = wt +
                ((size_t)((chunk * 9 + tap) * 2 + lhi) * 128 + wm * 64 + l31) * 8;
            bf16x8 a0 = *(const bf16x8*)&wg[0];
            bf16x8 a1 = *(const bf16x8*)&wg[32 * 8];
            const bf16* xb = &Xb[((dh * 2 + lhi) * 288 + dw * 16 + wn * 128 + l31) * 8];
            bf16x8 b0 = *(const bf16x8*)&xb[0];
            bf16x8 b1 = *(const bf16x8*)&xb[32 * 8];
            bf16x8 b2 = *(const bf16x8*)&xb[64 * 8];
            bf16x8 b3 = *(const bf16x8*)&xb[96 * 8];
            acc[0][0] = __builtin_amdgcn_mfma_f32_32x32x16_bf16(a0, b0, acc[0][0], 0, 0, 0);
            acc[0][1] = __builtin_amdgcn_mfma_f32_32x32x16_bf16(a0, b1, acc[0][1], 0, 0, 0);
            acc[0][2] = __builtin_amdgcn_mfma_f32_32x32x16_bf16(a0, b2, acc[0][2], 0, 0, 0);
            acc[0][3] = __builtin_amdgcn_mfma_f32_32x32x16_bf16(a0, b3, acc[0][3], 0, 0, 0);
            acc[1][0] = __builtin_amdgcn_mfma_f32_32x32x16_bf16(a1, b0, acc[1][0], 0, 0, 0);
            acc[1][1] = __builtin_amdgcn_mfma_f32_32x32x16_bf16(a1, b1, acc[1][1], 0, 0, 0);
            acc[1][2] = __builtin_amdgcn_mfma_f32_32x32x16_bf16(a1, b2, acc[1][2], 0, 0, 0);
            acc[1][3] = __builtin_amdgcn_mfma_f32_32x32x16_bf16(a1, b3, acc[1][3], 0, 0, 0);
        }

        __builtin_amdgcn_sched_barrier(0);
        __builtin_amdgcn_s_barrier();                // readers of buf[chunk&1] done
    }

    // epilogue: D col = lane&31 (elem), row = (reg&3)+8*(reg>>2)+4*lhi (co)
#pragma unroll
    for (int fm = 0; fm < 2; ++fm) {
        int cob = wm * 64 + fm * 32 + 4 * lhi;
#pragma unroll
        for (int q = 0; q < 4; ++q) {
            int co4 = cob + 8 * q;
            f32x4 sg = *(const f32x4*)&sig_inv[b * 128 + co4];
            f32x4 np4 = *(const f32x4*)&npar[co4];
            f32x4 bp4 = *(const f32x4*)&bpar[co4];
#pragma unroll
            for (int r = 0; r < 4; ++r) {
                int co = co4 + r;
                float* orow = out + ((size_t)(b * 128 + co) * 64 + h) * 1024 +
                              w0 * 16 + wn * 128;
#pragma unroll
                for (int nf = 0; nf < 4; ++nf) {
                    float v = acc[fm][nf][q * 4 + r];
                    orow[nf * 32 + l31] = v * sg[r] + np4[r] * ns[nf] + bp4[r];
                }
            }
        }
    }
}

// ---------------- fp32 fallback (ws too small) ----------------
__global__ void k_naive(const float* __restrict__ x, const float* __restrict__ weight,
                        const float* __restrict__ s, const float* __restrict__ sig,
                        const float* __restrict__ npar, const float* __restrict__ bpar,
                        const float* __restrict__ noise, float* __restrict__ out) {
    size_t o = (size_t)blockIdx.x * 256 + threadIdx.x;
    int t = o & 15, w = (o >> 4) & 63, h = (o >> 10) & 63;
    int co = (o >> 16) & 127, b = (int)(o >> 23);
    float a = 0.f;
    for (int ci = 0; ci < 128; ++ci) {
        const float* xr = x + (size_t)(b * 128 + ci) * 65536;
        const float* wr = weight + ((size_t)co * 128 + ci) * 9;
        float p = 0.f;
#pragma unroll
        for (int kh = 0; kh < 3; ++kh) {
            int ha = h + kh - 1;
            if ((unsigned)ha >= 64u) continue;
#pragma unroll
            for (int kw = 0; kw < 3; ++kw) {
                int wa = w + kw - 1;
                if ((unsigned)wa >= 64u) continue;
                p += xr[(ha * 64 + wa) * 16 + t] * wr[kh * 3 + kw];
            }
        }
        a += p * s[b * 128 + ci];
    }
    int E = b * 65536 + (h * 64 + w) * 16 + t;
    out[o] = a * sig[b * 128 + co] + npar[co] * noise[E] + bpar[co];
}

// ---------------- host ----------------
extern "C" void kernel_launch(void* const* d_in, const int* in_sizes, int n_in,
                              void* d_out, int out_size, void* d_ws, size_t ws_size,
                              hipStream_t stream) {
    const float* x      = (const float*)d_in[0];
    const float* style  = (const float*)d_in[1];
    const float* noise  = (const float*)d_in[2];
    const float* weight = (const float*)d_in[3];
    const float* sw     = (const float*)d_in[4];
    const float* sb     = (const float*)d_in[5];
    const float* npar   = (const float*)d_in[6];
    const float* bpar   = (const float*)d_in[7];
    float* out = (float*)d_out;

    float* s_buf   = (float*)d_ws;                         // 512 f32
    float* sig_buf = s_buf + 512;                          // 512 f32
    float* guard   = (float*)((char*)d_ws + 4096);         // 4096 B zeros
    bf16*  wt      = (bf16*)((char*)d_ws + 8192);          // 294912 B
    bf16*  xt      = (bf16*)((char*)d_ws + 8192 + 294912); // 67108864 B
    const size_t NEED = 8192 + 294912 + 67108864ull;

    k_style<<<dim3(128), dim3(256), 0, stream>>>(style, sw, sb, s_buf, guard);
    k_sig<<<dim3(128), dim3(256), 0, stream>>>(weight, s_buf, sig_buf);
    if (ws_size >= NEED) {
        k_wt<<<dim3(576), dim3(256), 0, stream>>>(weight, wt);
        k_xt<<<dim3(1024), dim3(256), 0, stream>>>(x, s_buf, xt);
        conv_main<<<dim3(4, 64, 4), dim3(256), 0, stream>>>(
            xt, wt, sig_buf, npar, bpar, noise, (const bf16*)guard, out);
    } else {
        k_naive<<<dim3(131072), dim3(256), 0, stream>>>(
            x, weight, s_buf, sig_buf, npar, bpar, noise, out);
    }
}

// Round 5
// 138.617 us; speedup vs baseline: 1.0113x; 1.0113x over previous
//
#include <hip/hip_runtime.h>
#include <hip/hip_bf16.h>
#include <stdint.h>

typedef __bf16 bf16;
typedef bf16 bf16x8 __attribute__((ext_vector_type(8)));
typedef float f32x4 __attribute__((ext_vector_type(4)));
typedef float f32x16 __attribute__((ext_vector_type(16)));

#define AS1 __attribute__((address_space(1)))
#define AS3 __attribute__((address_space(3)))

__device__ __forceinline__ void async_copy16(const void* g, void* l) {
    __builtin_amdgcn_global_load_lds((const AS1 uint32_t*)(g),
                                     (AS3 uint32_t*)(l), 16, 0, 0);
}

template <int N> __device__ __forceinline__ void waitv();
template <> __device__ __forceinline__ void waitv<0>()  { asm volatile("s_waitcnt vmcnt(0)"  ::: "memory"); }
template <> __device__ __forceinline__ void waitv<1>()  { asm volatile("s_waitcnt vmcnt(1)"  ::: "memory"); }
template <> __device__ __forceinline__ void waitv<2>()  { asm volatile("s_waitcnt vmcnt(2)"  ::: "memory"); }
template <> __device__ __forceinline__ void waitv<3>()  { asm volatile("s_waitcnt vmcnt(3)"  ::: "memory"); }
template <> __device__ __forceinline__ void waitv<4>()  { asm volatile("s_waitcnt vmcnt(4)"  ::: "memory"); }
template <> __device__ __forceinline__ void waitv<11>() { asm volatile("s_waitcnt vmcnt(11)" ::: "memory"); }

// ---------------- tiny prep kernels ----------------

// s[b,c] = style[b,:] . style_w[c,:] + style_b[c]; block 0 zeroes DMA guard.
__global__ void k_style(const float* __restrict__ style, const float* __restrict__ sw,
                        const float* __restrict__ sbias, float* __restrict__ s_out,
                        float* __restrict__ guard) {
    if (blockIdx.x == 0) {
#pragma unroll
        for (int j = 0; j < 4; ++j) guard[threadIdx.x + 256 * j] = 0.f;
    }
    int gw = (blockIdx.x * blockDim.x + threadIdx.x) >> 6;
    int lane = threadIdx.x & 63;
    if (gw >= 512) return;
    int b = gw >> 7, c = gw & 127;
    const float* st = style + b * 512;
    const float* wr = sw + c * 512;
    float a = 0.f;
#pragma unroll
    for (int j = 0; j < 8; ++j) a += st[lane + 64 * j] * wr[lane + 64 * j];
    for (int off = 32; off > 0; off >>= 1) a += __shfl_down(a, off, 64);
    if (lane == 0) s_out[gw] = a + sbias[c];
}

// sig_inv[b,o] = rsqrt( sum_i (sum_tap W[o,i,tap]^2) * s[b,i]^2 + 1e-8 )
__global__ void k_sig(const float* __restrict__ weight, const float* __restrict__ s,
                      float* __restrict__ sig) {
    int gw = (blockIdx.x * blockDim.x + threadIdx.x) >> 6;
    int lane = threadIdx.x & 63;
    if (gw >= 512) return;
    int b = gw >> 7, o = gw & 127;
    float a = 0.f;
#pragma unroll
    for (int j = 0; j < 2; ++j) {
        int i = lane + 64 * j;
        const float* wr = weight + ((size_t)o * 128 + i) * 9;
        float wsq = 0.f;
#pragma unroll
        for (int t = 0; t < 9; ++t) wsq += wr[t] * wr[t];
        float sv = s[b * 128 + i];
        a += wsq * sv * sv;
    }
    for (int off = 32; off > 0; off >>= 1) a += __shfl_down(a, off, 64);
    if (lane == 0) sig[gw] = rsqrtf(a + 1e-8f);
}

// repack weight fp32 [co][ci][9] -> bf16 wt[chunk8][tap9][g2][co128][8ci]
__global__ void k_wt(const float* __restrict__ weight, bf16* __restrict__ wt) {
    int i = blockIdx.x * 256 + threadIdx.x;
    if (i >= 147456) return;
    int j = i & 7;
    int co = (i >> 3) & 127;
    int g = (i >> 10) & 1;
    int tap = (i >> 11) % 9;
    int chunk = (i >> 11) / 9;
    int ci = chunk * 16 + g * 8 + j;
    wt[i] = (bf16)weight[((size_t)co * 128 + ci) * 9 + tap];
}

// x fp32 [b][ci][hwt] * s[b][ci] -> bf16 xt[b][g=ci>>3][e=hwt][8ci]
__global__ void k_xt(const float* __restrict__ x, const float* __restrict__ s,
                     bf16* __restrict__ xt) {
    int E = blockIdx.x * 256 + threadIdx.x;   // 0..262143
    int b = E >> 16, e = E & 65535;
    const float* xb = x + (size_t)b * 8388608 + e;
    const float* sb = s + b * 128;
#pragma unroll 4
    for (int g = 0; g < 16; ++g) {
        bf16x8 v;
#pragma unroll
        for (int j = 0; j < 8; ++j)
            v[j] = (bf16)(xb[(size_t)(g * 8 + j) * 65536] * sb[g * 8 + j]);
        *(bf16x8*)(xt + ((((size_t)b * 16 + g) << 16) + e) * 8) = v;
    }
}

// ---------------- main MFMA conv kernel ----------------
// grid (4 wblk, 64 h, 4 b); block 256 = 4 waves; tile 128co x 256elem.
// Diagnosis r4: vmcnt retires IN ORDER, so A-loads (wt) issued after the X
// staging DMAs forced a full vmcnt(0) drain at the first tap of every chunk.
// Fix: W also goes global->LDS via the DMA engine, as a 6-slot ring of 4KB
// tap-slabs prefetched 4 taps ahead; A-frags are then ds_read (lgkmcnt
// domain). Per-tap phase: {issue slab DMA (+X burst at tap1) -> counted
// vmcnt -> barrier -> 6 ds_read -> 8 MFMA}. No vmcnt drain in the loop.
// vmcnt literals (derived from static issue order; per-wave counts:
// X burst = 7, slab = 1):
//   steady chunks c=0..6: tap0:4  tap1:11(X just issued)  tap2-4:11  tap5-8:4
//   chunk 7 (no X, slab issue stops after tap4): tap0-4:4, tap5:3,6:2,7:1,8:0
// Ring/X WAR safety: per-tap barrier lockstep => wave skew < 1 phase; slot g
// is overwritten by slab g+6 issued 2 phases after g's readers finished.
__global__ __launch_bounds__(256, 2) void conv_main(
    const bf16* __restrict__ xt, const bf16* __restrict__ wt,
    const float* __restrict__ sig_inv, const float* __restrict__ npar,
    const float* __restrict__ bpar, const float* __restrict__ noise,
    const bf16* __restrict__ guard, float* __restrict__ out) {
    __shared__ bf16 Xl[2][1728 * 8];   // 2 x 27648 B  [dh3][g2][e288][8ci]
    __shared__ bf16 Wl[6 * 2048];      // 24576 B: 6-slot ring of 4KB tap-slabs
    __shared__ bf16 Xd[64 * 8];        // 1 KB dummy sink for X DMA padding

    const int tid = threadIdx.x;
    const int lane = tid & 63;
    const int l31 = lane & 31, lhi = lane >> 5;
    const int wm = (tid >> 6) & 1, wn = tid >> 7;
    const int w0 = blockIdx.x * 16;
    const int h = blockIdx.y;
    const int b = blockIdx.z;
    const size_t bHW = (size_t)b * 65536;

    // stage one X chunk: 1728 real cells + 64 dummy so EVERY wave issues
    // exactly 7 DMAs (uniform vmcnt accounting). OOB lanes read zero guard.
    auto stage = [&](int chunk, bf16* buf) {
#pragma unroll
        for (int it = 0; it < 7; ++it) {
            int u = it * 256 + tid;
            bool real = u < 1728;
            int ur = real ? u : 0;
            int dh = ur / 576;
            int rem = ur - dh * 576;
            int g = rem / 288;
            int e = rem - g * 288;
            int ha = h - 1 + dh;
            int wa = w0 - 1 + (e >> 4);
            bool ok = real & ((unsigned)ha < 64u) & ((unsigned)wa < 64u);
            int E = (ha * 64 + wa) * 16 + (e & 15);
            const bf16* gsrc = ok
                ? xt + ((((size_t)b * 16 + chunk * 2 + g) << 16) + E) * 8
                : guard;
            bf16* dst = real ? &buf[u * 8] : &Xd[(u - 1728) * 8];
            async_copy16(gsrc, dst);
        }
    };

    // one 4KB W tap-slab (= wt block for global tap g): 1 DMA per thread.
    auto slab_dma = [&](int g, int slot) {
        async_copy16(wt + (size_t)g * 2048 + tid * 8, &Wl[slot * 2048 + tid * 8]);
    };

    f32x16 acc[2][4] = {};

    // noise prefetch first: oldest in vmcnt, retired by the first counted wait
    const size_t ebase = bHW + (size_t)h * 1024 + w0 * 16 + wn * 128;
    float ns[4];
#pragma unroll
    for (int nf = 0; nf < 4; ++nf) ns[nf] = noise[ebase + nf * 32 + l31];

    // prologue: X(0) burst + W slabs 0..3
    stage(0, Xl[0]);
#pragma unroll
    for (int g = 0; g < 4; ++g) slab_dma(g, g);

#define TAP(c, t, LITN, DOX, DOSLAB)                                           \
    {                                                                          \
        if (DOX) stage((c) + 1, Xl[((c) + 1) & 1]);                            \
        if (DOSLAB) {                                                          \
            int so_ = sbase + (t) + 4;                                         \
            if (so_ >= 6) so_ -= 6;                                            \
            if (so_ >= 6) so_ -= 6;                                            \
            slab_dma((c) * 9 + (t) + 4, so_);                                  \
        }                                                                      \
        waitv<LITN>();                                                         \
        __builtin_amdgcn_sched_barrier(0);                                     \
        __builtin_amdgcn_s_barrier();                                          \
        {                                                                      \
            int sl_ = sbase + (t);                                             \
            if (sl_ >= 6) sl_ -= 6;                                            \
            const bf16* wg = &Wl[sl_ * 2048 + (lhi * 128 + wm * 64 + l31) * 8];\
            bf16x8 a0 = *(const bf16x8*)&wg[0];                                \
            bf16x8 a1 = *(const bf16x8*)&wg[32 * 8];                           \
            const int dh = (t) / 3, dw = (t) % 3;                              \
            const bf16* xb =                                                   \
                &Xb[((dh * 2 + lhi) * 288 + dw * 16 + wn * 128 + l31) * 8];    \
            bf16x8 b0 = *(const bf16x8*)&xb[0];                                \
            bf16x8 b1 = *(const bf16x8*)&xb[32 * 8];                           \
            bf16x8 b2 = *(const bf16x8*)&xb[64 * 8];                           \
            bf16x8 b3 = *(const bf16x8*)&xb[96 * 8];                           \
            acc[0][0] = __builtin_amdgcn_mfma_f32_32x32x16_bf16(a0, b0, acc[0][0], 0, 0, 0); \
            acc[0][1] = __builtin_amdgcn_mfma_f32_32x32x16_bf16(a0, b1, acc[0][1], 0, 0, 0); \
            acc[0][2] = __builtin_amdgcn_mfma_f32_32x32x16_bf16(a0, b2, acc[0][2], 0, 0, 0); \
            acc[0][3] = __builtin_amdgcn_mfma_f32_32x32x16_bf16(a0, b3, acc[0][3], 0, 0, 0); \
            acc[1][0] = __builtin_amdgcn_mfma_f32_32x32x16_bf16(a1, b0, acc[1][0], 0, 0, 0); \
            acc[1][1] = __builtin_amdgcn_mfma_f32_32x32x16_bf16(a1, b1, acc[1][1], 0, 0, 0); \
            acc[1][2] = __builtin_amdgcn_mfma_f32_32x32x16_bf16(a1, b2, acc[1][2], 0, 0, 0); \
            acc[1][3] = __builtin_amdgcn_mfma_f32_32x32x16_bf16(a1, b3, acc[1][3], 0, 0, 0); \
        }                                                                      \
    }

    for (int c = 0; c < 7; ++c) {
        const bf16* Xb = Xl[c & 1];
        const int sbase = (c & 1) * 3;   // (c*9) % 6
        TAP(c, 0, 4,  false, true);
        TAP(c, 1, 11, true,  true);      // X(c+1) burst, then slab: order matters
        TAP(c, 2, 11, false, true);
        TAP(c, 3, 11, false, true);
        TAP(c, 4, 11, false, true);
        TAP(c, 5, 4,  false, true);
        TAP(c, 6, 4,  false, true);
        TAP(c, 7, 4,  false, true);
        TAP(c, 8, 4,  false, true);
    }
    {   // chunk 7: no X burst; slab issues end after tap 4 (g caps at 71)
        const bf16* Xb = Xl[1];
        const int sbase = 3;
        TAP(7, 0, 4, false, true);
        TAP(7, 1, 4, false, true);
        TAP(7, 2, 4, false, true);
        TAP(7, 3, 4, false, true);
        TAP(7, 4, 4, false, true);
        TAP(7, 5, 3, false, false);
        TAP(7, 6, 2, false, false);
        TAP(7, 7, 1, false, false);
        TAP(7, 8, 0, false, false);
    }
#undef TAP

    // epilogue: D col = lane&31 (elem), row = (reg&3)+8*(reg>>2)+4*lhi (co)
#pragma unroll
    for (int fm = 0; fm < 2; ++fm) {
        int cob = wm * 64 + fm * 32 + 4 * lhi;
#pragma unroll
        for (int q = 0; q < 4; ++q) {
            int co4 = cob + 8 * q;
            f32x4 sg = *(const f32x4*)&sig_inv[b * 128 + co4];
            f32x4 np4 = *(const f32x4*)&npar[co4];
            f32x4 bp4 = *(const f32x4*)&bpar[co4];
#pragma unroll
            for (int r = 0; r < 4; ++r) {
                int co = co4 + r;
                float* orow = out + ((size_t)(b * 128 + co) * 64 + h) * 1024 +
                              w0 * 16 + wn * 128;
#pragma unroll
                for (int nf = 0; nf < 4; ++nf) {
                    float v = acc[fm][nf][q * 4 + r];
                    orow[nf * 32 + l31] = v * sg[r] + np4[r] * ns[nf] + bp4[r];
                }
            }
        }
    }
}

// ---------------- fp32 fallback (ws too small) ----------------
__global__ void k_naive(const float* __restrict__ x, const float* __restrict__ weight,
                        const float* __restrict__ s, const float* __restrict__ sig,
                        const float* __restrict__ npar, const float* __restrict__ bpar,
                        const float* __restrict__ noise, float* __restrict__ out) {
    size_t o = (size_t)blockIdx.x * 256 + threadIdx.x;
    int t = o & 15, w = (o >> 4) & 63, h = (o >> 10) & 63;
    int co = (o >> 16) & 127, b = (int)(o >> 23);
    float a = 0.f;
    for (int ci = 0; ci < 128; ++ci) {
        const float* xr = x + (size_t)(b * 128 + ci) * 65536;
        const float* wr = weight + ((size_t)co * 128 + ci) * 9;
        float p = 0.f;
#pragma unroll
        for (int kh = 0; kh < 3; ++kh) {
            int ha = h + kh - 1;
            if ((unsigned)ha >= 64u) continue;
#pragma unroll
            for (int kw = 0; kw < 3; ++kw) {
                int wa = w + kw - 1;
                if ((unsigned)wa >= 64u) continue;
                p += xr[(ha * 64 + wa) * 16 + t] * wr[kh * 3 + kw];
            }
        }
        a += p * s[b * 128 + ci];
    }
    int E = b * 65536 + (h * 64 + w) * 16 + t;
    out[o] = a * sig[b * 128 + co] + npar[co] * noise[E] + bpar[co];
}

// ---------------- host ----------------
extern "C" void kernel_launch(void* const* d_in, const int* in_sizes, int n_in,
                              void* d_out, int out_size, void* d_ws, size_t ws_size,
                              hipStream_t stream) {
    const float* x      = (const float*)d_in[0];
    const float* style  = (const float*)d_in[1];
    const float* noise  = (const float*)d_in[2];
    const float* weight = (const float*)d_in[3];
    const float* sw     = (const float*)d_in[4];
    const float* sb     = (const float*)d_in[5];
    const float* npar   = (const float*)d_in[6];
    const float* bpar   = (const float*)d_in[7];
    float* out = (float*)d_out;

    float* s_buf   = (float*)d_ws;                         // 512 f32
    float* sig_buf = s_buf + 512;                          // 512 f32
    float* guard   = (float*)((char*)d_ws + 4096);         // 4096 B zeros
    bf16*  wt      = (bf16*)((char*)d_ws + 8192);          // 294912 B
    bf16*  xt      = (bf16*)((char*)d_ws + 8192 + 294912); // 67108864 B
    const size_t NEED = 8192 + 294912 + 67108864ull;

    k_style<<<dim3(128), dim3(256), 0, stream>>>(style, sw, sb, s_buf, guard);
    k_sig<<<dim3(128), dim3(256), 0, stream>>>(weight, s_buf, sig_buf);
    if (ws_size >= NEED) {
        k_wt<<<dim3(576), dim3(256), 0, stream>>>(weight, wt);
        k_xt<<<dim3(1024), dim3(256), 0, stream>>>(x, s_buf, xt);
        conv_main<<<dim3(4, 64, 4), dim3(256), 0, stream>>>(
            xt, wt, sig_buf, npar, bpar, noise, (const bf16*)guard, out);
    } else {
        k_naive<<<dim3(131072), dim3(256), 0, stream>>>(
            x, weight, s_buf, sig_buf, npar, bpar, noise, out);
    }
}

// Round 6
// 137.001 us; speedup vs baseline: 1.0232x; 1.0118x over previous
//
#include <hip/hip_runtime.h>
#include <hip/hip_bf16.h>
#include <stdint.h>

typedef __bf16 bf16;
typedef bf16 bf16x8 __attribute__((ext_vector_type(8)));
typedef float f32x4 __attribute__((ext_vector_type(4)));
typedef float f32x16 __attribute__((ext_vector_type(16)));

#define AS1 __attribute__((address_space(1)))
#define AS3 __attribute__((address_space(3)))

__device__ __forceinline__ void async_copy16(const void* g, void* l) {
    __builtin_amdgcn_global_load_lds((const AS1 uint32_t*)(g),
                                     (AS3 uint32_t*)(l), 16, 0, 0);
}

template <int N> __device__ __forceinline__ void waitv();
template <> __device__ __forceinline__ void waitv<0>() { asm volatile("s_waitcnt vmcnt(0)" ::: "memory"); }
template <> __device__ __forceinline__ void waitv<1>() { asm volatile("s_waitcnt vmcnt(1)" ::: "memory"); }
template <> __device__ __forceinline__ void waitv<2>() { asm volatile("s_waitcnt vmcnt(2)" ::: "memory"); }
template <> __device__ __forceinline__ void waitv<3>() { asm volatile("s_waitcnt vmcnt(3)" ::: "memory"); }
template <> __device__ __forceinline__ void waitv<4>() { asm volatile("s_waitcnt vmcnt(4)" ::: "memory"); }
template <> __device__ __forceinline__ void waitv<8>() { asm volatile("s_waitcnt vmcnt(8)" ::: "memory"); }

// ---------------- tiny prep kernels ----------------

// s[b,c] = style[b,:] . style_w[c,:] + style_b[c]; block 0 zeroes DMA guard.
__global__ void k_style(const float* __restrict__ style, const float* __restrict__ sw,
                        const float* __restrict__ sbias, float* __restrict__ s_out,
                        float* __restrict__ guard) {
    if (blockIdx.x == 0) {
#pragma unroll
        for (int j = 0; j < 4; ++j) guard[threadIdx.x + 256 * j] = 0.f;
    }
    int gw = (blockIdx.x * blockDim.x + threadIdx.x) >> 6;
    int lane = threadIdx.x & 63;
    if (gw >= 512) return;
    int b = gw >> 7, c = gw & 127;
    const float* st = style + b * 512;
    const float* wr = sw + c * 512;
    float a = 0.f;
#pragma unroll
    for (int j = 0; j < 8; ++j) a += st[lane + 64 * j] * wr[lane + 64 * j];
    for (int off = 32; off > 0; off >>= 1) a += __shfl_down(a, off, 64);
    if (lane == 0) s_out[gw] = a + sbias[c];
}

// sig_inv[b,o] = rsqrt( sum_i (sum_tap W[o,i,tap]^2) * s[b,i]^2 + 1e-8 )
__global__ void k_sig(const float* __restrict__ weight, const float* __restrict__ s,
                      float* __restrict__ sig) {
    int gw = (blockIdx.x * blockDim.x + threadIdx.x) >> 6;
    int lane = threadIdx.x & 63;
    if (gw >= 512) return;
    int b = gw >> 7, o = gw & 127;
    float a = 0.f;
#pragma unroll
    for (int j = 0; j < 2; ++j) {
        int i = lane + 64 * j;
        const float* wr = weight + ((size_t)o * 128 + i) * 9;
        float wsq = 0.f;
#pragma unroll
        for (int t = 0; t < 9; ++t) wsq += wr[t] * wr[t];
        float sv = s[b * 128 + i];
        a += wsq * sv * sv;
    }
    for (int off = 32; off > 0; off >>= 1) a += __shfl_down(a, off, 64);
    if (lane == 0) sig[gw] = rsqrtf(a + 1e-8f);
}

// repack weight fp32 [co][ci][9] -> bf16 wt[chunk8][tap9][g2][co128][8ci]
__global__ void k_wt(const float* __restrict__ weight, bf16* __restrict__ wt) {
    int i = blockIdx.x * 256 + threadIdx.x;
    if (i >= 147456) return;
    int j = i & 7;
    int co = (i >> 3) & 127;
    int g = (i >> 10) & 1;
    int tap = (i >> 11) % 9;
    int chunk = (i >> 11) / 9;
    int ci = chunk * 16 + g * 8 + j;
    wt[i] = (bf16)weight[((size_t)co * 128 + ci) * 9 + tap];
}

// x fp32 [b][ci][hwt] * s[b][ci] -> bf16 xt[b][g=ci>>3][e=hwt][8ci]
__global__ void k_xt(const float* __restrict__ x, const float* __restrict__ s,
                     bf16* __restrict__ xt) {
    int E = blockIdx.x * 256 + threadIdx.x;   // 0..262143
    int b = E >> 16, e = E & 65535;
    const float* xb = x + (size_t)b * 8388608 + e;
    const float* sb = s + b * 128;
#pragma unroll 4
    for (int g = 0; g < 16; ++g) {
        bf16x8 v;
#pragma unroll
        for (int j = 0; j < 8; ++j)
            v[j] = (bf16)(xb[(size_t)(g * 8 + j) * 65536] * sb[g * 8 + j]);
        *(bf16x8*)(xt + ((((size_t)b * 16 + g) << 16) + e) * 8) = v;
    }
}

// ---------------- main MFMA conv kernel ----------------
// grid (4 wblk, 64 h, 4 b); block 512 = 8 waves; tile 128co x 256elem.
// r6 change vs r5: (1) OCCUPANCY: wave tile 64co x 64el -> acc[2][2] = 64
// AGPR + ~64 arch VGPR under (512,4) => 4 waves/SIMD, 16 waves/CU (r5 was 2;
// every pipe sat <=36% => TLP-starved). (2) X burst moved from tap1 to tap4
// (AFTER that tap's slab issue) so X is the YOUNGEST op in every mid-chunk
// wait window -- r5's tap-5 slab wait force-drained X (in-order retirement).
// Per-wave DMA counts kept uniform by duplicate-issue padding (dup waves
// copy identical bytes to identical LDS addresses -- benign; the post-wait
// s_barrier orders all waves' copies before any read).
// vmcnt literals (per wave: slab=1/tap, X=4 at tap4):
//   steady chunks c=0..6: taps0-3: 4, taps4-8: 8
//   chunk 7 (no X, slab issue ends at tap4): taps0-4: 4, then 3,2,1,0.
__global__ __launch_bounds__(512, 4) void conv_main(
    const bf16* __restrict__ xt, const bf16* __restrict__ wt,
    const float* __restrict__ sig_inv, const float* __restrict__ npar,
    const float* __restrict__ bpar, const float* __restrict__ noise,
    const bf16* __restrict__ guard, float* __restrict__ out) {
    __shared__ bf16 Xl[2][1728 * 8];   // 2 x 27648 B  [dh3][g2][e288][8ci]
    __shared__ bf16 Wl[6 * 2048];      // 24576 B: 6-slot ring of 4KB tap-slabs

    const int tid = threadIdx.x;
    const int lane = tid & 63;
    const int l31 = lane & 31, lhi = lane >> 5;
    const int wm = (tid >> 6) & 1;     // co half (64co)
    const int wn = tid >> 7;           // el quarter (64el), 0..3
    const int w0 = blockIdx.x * 16;
    const int h = blockIdx.y;
    const int b = blockIdx.z;
    const size_t bHW = (size_t)b * 65536;

    // stage one X chunk: 1728 cells in 4 iters of 512; iter 3 wraps (cells
    // 0..319 duplicated -- identical src/dst, benign). All waves: 4 DMAs.
    auto stage = [&](int chunk, bf16* buf) {
#pragma unroll
        for (int it = 0; it < 4; ++it) {
            int u0 = it * 512 + tid;
            int u = u0 >= 1728 ? u0 - 1728 : u0;
            int dh = u / 576;
            int rem = u - dh * 576;
            int g = rem / 288;
            int e = rem - g * 288;
            int ha = h - 1 + dh;
            int wa = w0 - 1 + (e >> 4);
            bool ok = ((unsigned)ha < 64u) & ((unsigned)wa < 64u);
            int E = (ha * 64 + wa) * 16 + (e & 15);
            const bf16* gsrc = ok
                ? xt + ((((size_t)b * 16 + chunk * 2 + g) << 16) + E) * 8
                : guard;
            async_copy16(gsrc, &buf[u * 8]);
        }
    };

    // one 4KB W tap-slab; tids 256..511 duplicate tids 0..255 (uniform count).
    auto slab_dma = [&](int g, int slot) {
        int t8 = tid & 255;
        async_copy16(wt + (size_t)g * 2048 + t8 * 8, &Wl[slot * 2048 + t8 * 8]);
    };

    f32x16 acc[2][2] = {};

    // noise prefetch first: oldest in vmcnt, retired by the first counted wait
    const size_t ebase = bHW + (size_t)h * 1024 + w0 * 16 + wn * 64;
    float ns[2];
#pragma unroll
    for (int nf = 0; nf < 2; ++nf) ns[nf] = noise[ebase + nf * 32 + l31];

    // prologue: X(0) burst + W slabs 0..3
    stage(0, Xl[0]);
#pragma unroll
    for (int g = 0; g < 4; ++g) slab_dma(g, g);

#define TAP(c, t, LITN, DOX, DOSLAB)                                           \
    {                                                                          \
        if (DOSLAB) {                                                          \
            int so_ = sbase + (t) + 4;                                         \
            if (so_ >= 6) so_ -= 6;                                            \
            if (so_ >= 6) so_ -= 6;                                            \
            slab_dma((c) * 9 + (t) + 4, so_);                                  \
        }                                                                      \
        if (DOX) stage((c) + 1, Xl[((c) + 1) & 1]);  /* youngest in queue */   \
        waitv<LITN>();                                                         \
        __builtin_amdgcn_sched_barrier(0);                                     \
        __builtin_amdgcn_s_barrier();                                          \
        {                                                                      \
            int sl_ = sbase + (t);                                             \
            if (sl_ >= 6) sl_ -= 6;                                            \
            const bf16* wg = &Wl[sl_ * 2048 + (lhi * 128 + wm * 64 + l31) * 8];\
            bf16x8 a0 = *(const bf16x8*)&wg[0];                                \
            bf16x8 a1 = *(const bf16x8*)&wg[32 * 8];                           \
            const int dh = (t) / 3, dw = (t) % 3;                              \
            const bf16* xb =                                                   \
                &Xb[((dh * 2 + lhi) * 288 + dw * 16 + wn * 64 + l31) * 8];     \
            bf16x8 b0 = *(const bf16x8*)&xb[0];                                \
            bf16x8 b1 = *(const bf16x8*)&xb[32 * 8];                           \
            acc[0][0] = __builtin_amdgcn_mfma_f32_32x32x16_bf16(a0, b0, acc[0][0], 0, 0, 0); \
            acc[0][1] = __builtin_amdgcn_mfma_f32_32x32x16_bf16(a0, b1, acc[0][1], 0, 0, 0); \
            acc[1][0] = __builtin_amdgcn_mfma_f32_32x32x16_bf16(a1, b0, acc[1][0], 0, 0, 0); \
            acc[1][1] = __builtin_amdgcn_mfma_f32_32x32x16_bf16(a1, b1, acc[1][1], 0, 0, 0); \
        }                                                                      \
    }

    for (int c = 0; c < 7; ++c) {
        const bf16* Xb = Xl[c & 1];
        const int sbase = (c & 1) * 3;   // (c*9) % 6
        TAP(c, 0, 4, false, true);
        TAP(c, 1, 4, false, true);
        TAP(c, 2, 4, false, true);
        TAP(c, 3, 4, false, true);
        TAP(c, 4, 8, true,  true);       // slab(t8) first, then X(c+1)
        TAP(c, 5, 8, false, true);
        TAP(c, 6, 8, false, true);
        TAP(c, 7, 8, false, true);
        TAP(c, 8, 8, false, true);
    }
    {   // chunk 7: no X burst; slab issues end after tap 4 (g caps at 71)
        const bf16* Xb = Xl[1];
        const int sbase = 3;
        TAP(7, 0, 4, false, true);
        TAP(7, 1, 4, false, true);
        TAP(7, 2, 4, false, true);
        TAP(7, 3, 4, false, true);
        TAP(7, 4, 4, false, true);
        TAP(7, 5, 3, false, false);
        TAP(7, 6, 2, false, false);
        TAP(7, 7, 1, false, false);
        TAP(7, 8, 0, false, false);
    }
#undef TAP

    // epilogue: D col = lane&31 (elem), row = (reg&3)+8*(reg>>2)+4*lhi (co)
#pragma unroll
    for (int fm = 0; fm < 2; ++fm) {
        int cob = wm * 64 + fm * 32 + 4 * lhi;
#pragma unroll
        for (int q = 0; q < 4; ++q) {
            int co4 = cob + 8 * q;
            f32x4 sg = *(const f32x4*)&sig_inv[b * 128 + co4];
            f32x4 np4 = *(const f32x4*)&npar[co4];
            f32x4 bp4 = *(const f32x4*)&bpar[co4];
#pragma unroll
            for (int r = 0; r < 4; ++r) {
                int co = co4 + r;
                float* orow = out + ((size_t)(b * 128 + co) * 64 + h) * 1024 +
                              w0 * 16 + wn * 64;
#pragma unroll
                for (int nf = 0; nf < 2; ++nf) {
                    float v = acc[fm][nf][q * 4 + r];
                    orow[nf * 32 + l31] = v * sg[r] + np4[r] * ns[nf] + bp4[r];
                }
            }
        }
    }
}

// ---------------- fp32 fallback (ws too small) ----------------
__global__ void k_naive(const float* __restrict__ x, const float* __restrict__ weight,
                        const float* __restrict__ s, const float* __restrict__ sig,
                        const float* __restrict__ npar, const float* __restrict__ bpar,
                        const float* __restrict__ noise, float* __restrict__ out) {
    size_t o = (size_t)blockIdx.x * 256 + threadIdx.x;
    int t = o & 15, w = (o >> 4) & 63, h = (o >> 10) & 63;
    int co = (o >> 16) & 127, b = (int)(o >> 23);
    float a = 0.f;
    for (int ci = 0; ci < 128; ++ci) {
        const float* xr = x + (size_t)(b * 128 + ci) * 65536;
        const float* wr = weight + ((size_t)co * 128 + ci) * 9;
        float p = 0.f;
#pragma unroll
        for (int kh = 0; kh < 3; ++kh) {
            int ha = h + kh - 1;
            if ((unsigned)ha >= 64u) continue;
#pragma unroll
            for (int kw = 0; kw < 3; ++kw) {
                int wa = w + kw - 1;
                if ((unsigned)wa >= 64u) continue;
                p += xr[(ha * 64 + wa) * 16 + t] * wr[kh * 3 + kw];
            }
        }
        a += p * s[b * 128 + ci];
    }
    int E = b * 65536 + (h * 64 + w) * 16 + t;
    out[o] = a * sig[b * 128 + co] + npar[co] * noise[E] + bpar[co];
}

// ---------------- host ----------------
extern "C" void kernel_launch(void* const* d_in, const int* in_sizes, int n_in,
                              void* d_out, int out_size, void* d_ws, size_t ws_size,
                              hipStream_t stream) {
    const float* x      = (const float*)d_in[0];
    const float* style  = (const float*)d_in[1];
    const float* noise  = (const float*)d_in[2];
    const float* weight = (const float*)d_in[3];
    const float* sw     = (const float*)d_in[4];
    const float* sb     = (const float*)d_in[5];
    const float* npar   = (const float*)d_in[6];
    const float* bpar   = (const float*)d_in[7];
    float* out = (float*)d_out;

    float* s_buf   = (float*)d_ws;                         // 512 f32
    float* sig_buf = s_buf + 512;                          // 512 f32
    float* guard   = (float*)((char*)d_ws + 4096);         // 4096 B zeros
    bf16*  wt      = (bf16*)((char*)d_ws + 8192);          // 294912 B
    bf16*  xt      = (bf16*)((char*)d_ws + 8192 + 294912); // 67108864 B
    const size_t NEED = 8192 + 294912 + 67108864ull;

    k_style<<<dim3(128), dim3(256), 0, stream>>>(style, sw, sb, s_buf, guard);
    k_sig<<<dim3(128), dim3(256), 0, stream>>>(weight, s_buf, sig_buf);
    if (ws_size >= NEED) {
        k_wt<<<dim3(576), dim3(256), 0, stream>>>(weight, wt);
        k_xt<<<dim3(1024), dim3(256), 0, stream>>>(x, s_buf, xt);
        conv_main<<<dim3(4, 64, 4), dim3(512), 0, stream>>>(
            xt, wt, sig_buf, npar, bpar, noise, (const bf16*)guard, out);
    } else {
        k_naive<<<dim3(131072), dim3(256), 0, stream>>>(
            x, weight, s_buf, sig_buf, npar, bpar, noise, out);
    }
}

// Round 8
// 135.686 us; speedup vs baseline: 1.0331x; 1.0097x over previous
//
#include <hip/hip_runtime.h>
#include <hip/hip_bf16.h>
#include <stdint.h>

typedef __bf16 bf16;
typedef bf16 bf16x8 __attribute__((ext_vector_type(8)));
typedef float f32x4 __attribute__((ext_vector_type(4)));
typedef float f32x16 __attribute__((ext_vector_type(16)));

#define AS1 __attribute__((address_space(1)))
#define AS3 __attribute__((address_space(3)))

__device__ __forceinline__ void async_copy16(const void* g, void* l) {
    __builtin_amdgcn_global_load_lds((const AS1 uint32_t*)(g),
                                     (AS3 uint32_t*)(l), 16, 0, 0);
}

template <int N> __device__ __forceinline__ void waitv();
template <> __device__ __forceinline__ void waitv<0>() { asm volatile("s_waitcnt vmcnt(0)" ::: "memory"); }
template <> __device__ __forceinline__ void waitv<6>() { asm volatile("s_waitcnt vmcnt(6)" ::: "memory"); }
template <> __device__ __forceinline__ void waitv<9>() { asm volatile("s_waitcnt vmcnt(9)" ::: "memory"); }

// ---------------- tiny prep kernels ----------------

// s[b,c] = style[b,:] . style_w[c,:] + style_b[c]; block 0 zeroes DMA guard.
__global__ void k_style(const float* __restrict__ style, const float* __restrict__ sw,
                        const float* __restrict__ sbias, float* __restrict__ s_out,
                        float* __restrict__ guard) {
    if (blockIdx.x == 0) {
#pragma unroll
        for (int j = 0; j < 4; ++j) guard[threadIdx.x + 256 * j] = 0.f;
    }
    int gw = (blockIdx.x * blockDim.x + threadIdx.x) >> 6;
    int lane = threadIdx.x & 63;
    if (gw >= 512) return;
    int b = gw >> 7, c = gw & 127;
    const float* st = style + b * 512;
    const float* wr = sw + c * 512;
    float a = 0.f;
#pragma unroll
    for (int j = 0; j < 8; ++j) a += st[lane + 64 * j] * wr[lane + 64 * j];
    for (int off = 32; off > 0; off >>= 1) a += __shfl_down(a, off, 64);
    if (lane == 0) s_out[gw] = a + sbias[c];
}

// sig_inv[b,o] = rsqrt( sum_i (sum_tap W[o,i,tap]^2) * s[b,i]^2 + 1e-8 )
__global__ void k_sig(const float* __restrict__ weight, const float* __restrict__ s,
                      float* __restrict__ sig) {
    int gw = (blockIdx.x * blockDim.x + threadIdx.x) >> 6;
    int lane = threadIdx.x & 63;
    if (gw >= 512) return;
    int b = gw >> 7, o = gw & 127;
    float a = 0.f;
#pragma unroll
    for (int j = 0; j < 2; ++j) {
        int i = lane + 64 * j;
        const float* wr = weight + ((size_t)o * 128 + i) * 9;
        float wsq = 0.f;
#pragma unroll
        for (int t = 0; t < 9; ++t) wsq += wr[t] * wr[t];
        float sv = s[b * 128 + i];
        a += wsq * sv * sv;
    }
    for (int off = 32; off > 0; off >>= 1) a += __shfl_down(a, off, 64);
    if (lane == 0) sig[gw] = rsqrtf(a + 1e-8f);
}

// repack weight fp32 [co][ci][9] -> bf16 wt[chunk8][tap9][g2][co128][8ci]
__global__ void k_wt(const float* __restrict__ weight, bf16* __restrict__ wt) {
    int i = blockIdx.x * 256 + threadIdx.x;
    if (i >= 147456) return;
    int j = i & 7;
    int co = (i >> 3) & 127;
    int g = (i >> 10) & 1;
    int tap = (i >> 11) % 9;
    int chunk = (i >> 11) / 9;
    int ci = chunk * 16 + g * 8 + j;
    wt[i] = (bf16)weight[((size_t)co * 128 + ci) * 9 + tap];
}

// x fp32 [b][ci][hwt] * s[b][ci] -> bf16 xt[b][g=ci>>3][e=hwt][8ci]
__global__ void k_xt(const float* __restrict__ x, const float* __restrict__ s,
                     bf16* __restrict__ xt) {
    int E = blockIdx.x * 256 + threadIdx.x;   // 0..262143
    int b = E >> 16, e = E & 65535;
    const float* xb = x + (size_t)b * 8388608 + e;
    const float* sb = s + b * 128;
#pragma unroll 4
    for (int g = 0; g < 16; ++g) {
        bf16x8 v;
#pragma unroll
        for (int j = 0; j < 8; ++j)
            v[j] = (bf16)(xb[(size_t)(g * 8 + j) * 65536] * sb[g * 8 + j]);
        *(bf16x8*)(xt + ((((size_t)b * 16 + g) << 16) + e) * 8) = v;
    }
}

// ---------------- main MFMA conv kernel ----------------
// grid (4 wblk, 64 h, 4 b); block 256 = 4 waves; tile 128co x 256elem.
// 24 coarse phases (one per dh-row = 3 taps): each phase = {issue W(p+1),
// issue X(p+2), vmcnt(9), barrier, 18 ds_read + 24 MFMA interleaved by the
// compiler}. Breaks the per-tap barrier convoy (r0/r5/r6: all pipes <37%).
// WAR-SAFE RINGS (r7's single-buffer restaging raced -- distance-1 write
// issued before the barrier that retires the readers):
//   X: 4-slot ring, row g staged at phase g-2 into slot g&3; overwrites row
//      g-4 whose readers finished before barrier g-3, which every wave
//      passes before any wave reaches phase g-2's issue point. SAFE.
//   W: 3-slot ring, slab s staged at phase s-1 (wt is L2-hot; one phase of
//      latency suffices); overwrites slab s-3, readers done before barrier
//      s-2. SAFE.
// vmcnt ledger (issue order [W(p+1):3, X(p+2):3] per wave, uniform):
//   prologue [noise:4, X0:3, W0:3, X1:3]; wait(p) must retire W(p),X(p) ->
//   remaining = X(p+1),W(p+1),X(p+2) = 9 -> vmcnt(9) at p=0..21;
//   p=22: vmcnt(6) (W23,X23 remain); p=23: vmcnt(0).
// LDS: 4*9216(X) + 3*12288(W) = 73728 B -> 2 blocks/CU.
__global__ __launch_bounds__(256, 2) void conv_main(
    const bf16* __restrict__ xt, const bf16* __restrict__ wt,
    const float* __restrict__ sig_inv, const float* __restrict__ npar,
    const float* __restrict__ bpar, const float* __restrict__ noise,
    const bf16* __restrict__ guard, float* __restrict__ out) {
    __shared__ bf16 Xr[4][576 * 8];    // 4 x 9216 B  X row ring [g2][e288][8ci]
    __shared__ bf16 Wr[3][768 * 8];    // 3 x 12288 B W dh-slab ring [dw3][g2][co128][8ci]

    const int tid = threadIdx.x;
    const int lane = tid & 63;
    const int l31 = lane & 31, lhi = lane >> 5;
    const int wm = (tid >> 6) & 1;     // co half (64co)
    const int wn = tid >> 7;           // el half (128el)
    const int w0 = blockIdx.x * 16;
    const int h = blockIdx.y;
    const int b = blockIdx.z;
    const size_t bHW = (size_t)b * 65536;

    // W dh-slab s (= 3*chunk + dh), 768 cells: exactly 3 DMAs per thread.
    auto wslab = [&](int s) {
        int slot = s % 3;
#pragma unroll
        for (int it = 0; it < 3; ++it) {
            int v = it * 256 + tid;
            async_copy16(wt + (size_t)s * 6144 + v * 8, &Wr[slot][v * 8]);
        }
    };

    // X row g (= 3*chunk + dh), 576 cells: 3 iters of 256, wrap-dup (192
    // duplicate cells, identical src+dst -- benign). OOB -> zero guard.
    auto xrow = [&](int g) {
        int slot = g & 3;
        int cg = g / 3, dhg = g - cg * 3;
#pragma unroll
        for (int it = 0; it < 3; ++it) {
            int v0 = it * 256 + tid;
            int v = v0 >= 576 ? v0 - 576 : v0;
            int gg = v / 288;
            int e = v - gg * 288;
            int ha = h - 1 + dhg;
            int wa = w0 - 1 + (e >> 4);
            bool ok = ((unsigned)ha < 64u) & ((unsigned)wa < 64u);
            int E = (ha * 64 + wa) * 16 + (e & 15);
            const bf16* gsrc = ok
                ? xt + ((((size_t)b * 16 + cg * 2 + gg) << 16) + E) * 8
                : guard;
            async_copy16(gsrc, &Xr[slot][v * 8]);
        }
    };

    f32x16 acc[2][4] = {};

    // noise prefetch first: oldest in vmcnt, retired by the first vmcnt(9)
    const size_t ebase = bHW + (size_t)h * 1024 + w0 * 16 + wn * 128;
    float ns[4];
#pragma unroll
    for (int nf = 0; nf < 4; ++nf) ns[nf] = noise[ebase + nf * 32 + l31];
    __builtin_amdgcn_sched_barrier(0);   // pin noise loads before the DMAs

    // prologue: X0, W0, X1 (order: retiring W0 also retires X0)
    xrow(0);  wslab(0);  xrow(1);

#define PHASE(c, dh, LIT, DOW, DOX)                                            \
    {                                                                          \
        if (DOW) wslab(3 * (c) + (dh) + 1);                                    \
        if (DOX) xrow(3 * (c) + (dh) + 2);                                     \
        waitv<LIT>();                                                          \
        __builtin_amdgcn_sched_barrier(0);                                     \
        __builtin_amdgcn_s_barrier();                                          \
        const int xs_ = (3 * (c) + (dh)) & 3;                                  \
        _Pragma("unroll")                                                      \
        for (int dw = 0; dw < 3; ++dw) {                                       \
            const bf16* wg =                                                   \
                &Wr[dh][((dw * 2 + lhi) * 128 + wm * 64 + l31) * 8];           \
            bf16x8 a0 = *(const bf16x8*)&wg[0];                                \
            bf16x8 a1 = *(const bf16x8*)&wg[32 * 8];                           \
            const bf16* xb =                                                   \
                &Xr[xs_][(lhi * 288 + dw * 16 + wn * 128 + l31) * 8];          \
            bf16x8 b0 = *(const bf16x8*)&xb[0];                                \
            bf16x8 b1 = *(const bf16x8*)&xb[32 * 8];                           \
            bf16x8 b2 = *(const bf16x8*)&xb[64 * 8];                           \
            bf16x8 b3 = *(const bf16x8*)&xb[96 * 8];                           \
            acc[0][0] = __builtin_amdgcn_mfma_f32_32x32x16_bf16(a0, b0, acc[0][0], 0, 0, 0); \
            acc[0][1] = __builtin_amdgcn_mfma_f32_32x32x16_bf16(a0, b1, acc[0][1], 0, 0, 0); \
            acc[0][2] = __builtin_amdgcn_mfma_f32_32x32x16_bf16(a0, b2, acc[0][2], 0, 0, 0); \
            acc[0][3] = __builtin_amdgcn_mfma_f32_32x32x16_bf16(a0, b3, acc[0][3], 0, 0, 0); \
            acc[1][0] = __builtin_amdgcn_mfma_f32_32x32x16_bf16(a1, b0, acc[1][0], 0, 0, 0); \
            acc[1][1] = __builtin_amdgcn_mfma_f32_32x32x16_bf16(a1, b1, acc[1][1], 0, 0, 0); \
            acc[1][2] = __builtin_amdgcn_mfma_f32_32x32x16_bf16(a1, b2, acc[1][2], 0, 0, 0); \
            acc[1][3] = __builtin_amdgcn_mfma_f32_32x32x16_bf16(a1, b3, acc[1][3], 0, 0, 0); \
        }                                                                      \
    }

    for (int c = 0; c < 7; ++c) {
        PHASE(c, 0, 9, true, true);
        PHASE(c, 1, 9, true, true);
        PHASE(c, 2, 9, true, true);
    }
    PHASE(7, 0, 9, true,  true);    // p=21: W22, X23
    PHASE(7, 1, 6, true,  false);   // p=22: W23 only
    PHASE(7, 2, 0, false, false);   // p=23: drain
#undef PHASE

    // epilogue: D col = lane&31 (elem), row = (reg&3)+8*(reg>>2)+4*lhi (co)
#pragma unroll
    for (int fm = 0; fm < 2; ++fm) {
        int cob = wm * 64 + fm * 32 + 4 * lhi;
#pragma unroll
        for (int q = 0; q < 4; ++q) {
            int co4 = cob + 8 * q;
            f32x4 sg = *(const f32x4*)&sig_inv[b * 128 + co4];
            f32x4 np4 = *(const f32x4*)&npar[co4];
            f32x4 bp4 = *(const f32x4*)&bpar[co4];
#pragma unroll
            for (int r = 0; r < 4; ++r) {
                int co = co4 + r;
                float* orow = out + ((size_t)(b * 128 + co) * 64 + h) * 1024 +
                              w0 * 16 + wn * 128;
#pragma unroll
                for (int nf = 0; nf < 4; ++nf) {
                    float v = acc[fm][nf][q * 4 + r];
                    orow[nf * 32 + l31] = v * sg[r] + np4[r] * ns[nf] + bp4[r];
                }
            }
        }
    }
}

// ---------------- fp32 fallback (ws too small) ----------------
__global__ void k_naive(const float* __restrict__ x, const float* __restrict__ weight,
                        const float* __restrict__ s, const float* __restrict__ sig,
                        const float* __restrict__ npar, const float* __restrict__ bpar,
                        const float* __restrict__ noise, float* __restrict__ out) {
    size_t o = (size_t)blockIdx.x * 256 + threadIdx.x;
    int t = o & 15, w = (o >> 4) & 63, h = (o >> 10) & 63;
    int co = (o >> 16) & 127, b = (int)(o >> 23);
    float a = 0.f;
    for (int ci = 0; ci < 128; ++ci) {
        const float* xr = x + (size_t)(b * 128 + ci) * 65536;
        const float* wr = weight + ((size_t)co * 128 + ci) * 9;
        float p = 0.f;
#pragma unroll
        for (int kh = 0; kh < 3; ++kh) {
            int ha = h + kh - 1;
            if ((unsigned)ha >= 64u) continue;
#pragma unroll
            for (int kw = 0; kw < 3; ++kw) {
                int wa = w + kw - 1;
                if ((unsigned)wa >= 64u) continue;
                p += xr[(ha * 64 + wa) * 16 + t] * wr[kh * 3 + kw];
            }
        }
        a += p * s[b * 128 + ci];
    }
    int E = b * 65536 + (h * 64 + w) * 16 + t;
    out[o] = a * sig[b * 128 + co] + npar[co] * noise[E] + bpar[co];
}

// ---------------- host ----------------
extern "C" void kernel_launch(void* const* d_in, const int* in_sizes, int n_in,
                              void* d_out, int out_size, void* d_ws, size_t ws_size,
                              hipStream_t stream) {
    const float* x      = (const float*)d_in[0];
    const float* style  = (const float*)d_in[1];
    const float* noise  = (const float*)d_in[2];
    const float* weight = (const float*)d_in[3];
    const float* sw     = (const float*)d_in[4];
    const float* sb     = (const float*)d_in[5];
    const float* npar   = (const float*)d_in[6];
    const float* bpar   = (const float*)d_in[7];
    float* out = (float*)d_out;

    float* s_buf   = (float*)d_ws;                         // 512 f32
    float* sig_buf = s_buf + 512;                          // 512 f32
    float* guard   = (float*)((char*)d_ws + 4096);         // 4096 B zeros
    bf16*  wt      = (bf16*)((char*)d_ws + 8192);          // 294912 B
    bf16*  xt      = (bf16*)((char*)d_ws + 8192 + 294912); // 67108864 B
    const size_t NEED = 8192 + 294912 + 67108864ull;

    k_style<<<dim3(128), dim3(256), 0, stream>>>(style, sw, sb, s_buf, guard);
    k_sig<<<dim3(128), dim3(256), 0, stream>>>(weight, s_buf, sig_buf);
    if (ws_size >= NEED) {
        k_wt<<<dim3(576), dim3(256), 0, stream>>>(weight, wt);
        k_xt<<<dim3(1024), dim3(256), 0, stream>>>(x, s_buf, xt);
        conv_main<<<dim3(4, 64, 4), dim3(256), 0, stream>>>(
            xt, wt, sig_buf, npar, bpar, noise, (const bf16*)guard, out);
    } else {
        k_naive<<<dim3(131072), dim3(256), 0, stream>>>(
            x, weight, s_buf, sig_buf, npar, bpar, noise, out);
    }
}

// Round 9
// 112.768 us; speedup vs baseline: 1.2431x; 1.2032x over previous
//
#include <hip/hip_runtime.h>
#include <hip/hip_bf16.h>
#include <stdint.h>

typedef __bf16 bf16;
typedef bf16 bf16x8 __attribute__((ext_vector_type(8)));
typedef float f32x4 __attribute__((ext_vector_type(4)));
typedef float f32x16 __attribute__((ext_vector_type(16)));

#define AS1 __attribute__((address_space(1)))
#define AS3 __attribute__((address_space(3)))

__device__ __forceinline__ void async_copy16(const void* g, void* l) {
    __builtin_amdgcn_global_load_lds((const AS1 uint32_t*)(g),
                                     (AS3 uint32_t*)(l), 16, 0, 0);
}

template <int N> __device__ __forceinline__ void waitv();
template <> __device__ __forceinline__ void waitv<0>()  { asm volatile("s_waitcnt vmcnt(0)"  ::: "memory"); }
template <> __device__ __forceinline__ void waitv<27>() { asm volatile("s_waitcnt vmcnt(27)" ::: "memory"); }

// ---------------- tiny prep kernels ----------------

// s[b,c] = style[b,:] . style_w[c,:] + style_b[c]
__global__ void k_style(const float* __restrict__ style, const float* __restrict__ sw,
                        const float* __restrict__ sbias, float* __restrict__ s_out) {
    int gw = (blockIdx.x * blockDim.x + threadIdx.x) >> 6;
    int lane = threadIdx.x & 63;
    if (gw >= 512) return;
    int b = gw >> 7, c = gw & 127;
    const float* st = style + b * 512;
    const float* wr = sw + c * 512;
    float a = 0.f;
#pragma unroll
    for (int j = 0; j < 8; ++j) a += st[lane + 64 * j] * wr[lane + 64 * j];
    for (int off = 32; off > 0; off >>= 1) a += __shfl_down(a, off, 64);
    if (lane == 0) s_out[gw] = a + sbias[c];
}

// sig_inv[b,o] = rsqrt( sum_i (sum_tap W[o,i,tap]^2) * s[b,i]^2 + 1e-8 )
__global__ void k_sig(const float* __restrict__ weight, const float* __restrict__ s,
                      float* __restrict__ sig) {
    int gw = (blockIdx.x * blockDim.x + threadIdx.x) >> 6;
    int lane = threadIdx.x & 63;
    if (gw >= 512) return;
    int b = gw >> 7, o = gw & 127;
    float a = 0.f;
#pragma unroll
    for (int j = 0; j < 2; ++j) {
        int i = lane + 64 * j;
        const float* wr = weight + ((size_t)o * 128 + i) * 9;
        float wsq = 0.f;
#pragma unroll
        for (int t = 0; t < 9; ++t) wsq += wr[t] * wr[t];
        float sv = s[b * 128 + i];
        a += wsq * sv * sv;
    }
    for (int off = 32; off > 0; off >>= 1) a += __shfl_down(a, off, 64);
    if (lane == 0) sig[gw] = rsqrtf(a + 1e-8f);
}

// repack + style-fold: fp32 W[co][ci][9] * s[b][ci] ->
// bf16 wt[b4][chunk8][tap9][g2][co128][8ci]   (r3's k_wt -- proven numerics)
__global__ void k_wt(const float* __restrict__ weight, const float* __restrict__ s,
                     bf16* __restrict__ wt) {
    int i = blockIdx.x * 256 + threadIdx.x;
    if (i >= 589824) return;
    int j = i & 7;
    int co = (i >> 3) & 127;
    int g = (i >> 10) & 1;
    int tap = (i >> 11) % 9;
    int cb = (i >> 11) / 9;      // chunk + 8*b
    int chunk = cb & 7, b = cb >> 3;
    int ci = chunk * 16 + g * 8 + j;
    wt[i] = (bf16)(weight[((size_t)co * 128 + ci) * 9 + tap] * s[b * 128 + ci]);
}

// ---------------- main MFMA conv kernel ----------------
// grid (4 wblk, 64 h, 4 b); block 256 = 4 waves; tile 128co x 256elem.
// r9 = r8's 24-coarse-phase machine + r3's data path (style folded into
// per-batch wt, X read directly from fp32 x): DELETES the 192MB k_xt pass.
// Per phase p (row = (chunk, dh) = p/3, p%3):
//   1. wslab(p+1): 3 global_load_lds DMAs (W ring slot (p+1)%3)
//   2. xstore(p): cvt XL regs (loaded phase p-1) -> bf16x8 -> 3 ds_write_b128
//      into X ring slot p%3. Compiler's implicit wait here is vmcnt(3)
//      (younger = W(p+1) only) -> retires XL(p)+W(p), keeps W(p+1) in flight.
//   3. xload(p+1): 24 fp32 global loads into XL regs (1 phase of lead)
//   4. vmcnt(27) (safety; usually no-op) ; lgkmcnt(0) flushes ds_writes
//   5. s_barrier ; compute(p): 18 ds_read_b128 + 24 MFMA
// Ring safety (3 slots each, write at phase p overwrites row/slab p-3):
// passing barrier(p-1) is collective => all waves finished compute(p-2)
// (and a fortiori compute(p-3), the last readers). SAFE.
// vmcnt ledger (per-wave uniform: 3 W DMAs + 24 XL loads per phase via
// wrap-dup cells; dup cells write identical values -- benign):
// steady 27; p=23 issues nothing, store's implicit vmcnt(0) drains.
// LDS: 3*9216(X) + 3*12288(W) = 64512 B -> 2 blocks/CU.
__global__ __launch_bounds__(256, 2) void conv_main(
    const float* __restrict__ x, const bf16* __restrict__ wt,
    const float* __restrict__ sig_inv, const float* __restrict__ npar,
    const float* __restrict__ bpar, const float* __restrict__ noise,
    float* __restrict__ out) {
    __shared__ bf16 Xr[3][576 * 8];    // 3 x 9216 B  X row ring [g2][e288][8ci]
    __shared__ bf16 Wr[3][768 * 8];    // 3 x 12288 B W dh-slab ring [dw3][g2][co128][8ci]

    const int tid = threadIdx.x;
    const int lane = tid & 63;
    const int l31 = lane & 31, lhi = lane >> 5;
    const int wm = (tid >> 6) & 1;     // co half (64co)
    const int wn = tid >> 7;           // el half (128el)
    const int w0 = blockIdx.x * 16;
    const int h = blockIdx.y;
    const int b = blockIdx.z;
    const size_t bHW = (size_t)b * 65536;
    const bf16* wb = wt + (size_t)b * 147456;

    float XL[24];                      // in-flight X row (3 cells x 8 ci)

    // W dh-slab s (= 3*chunk + dh): 768 cells, exactly 3 DMAs per thread.
    auto wslab = [&](int s) {
        int slot = s % 3;
#pragma unroll
        for (int it = 0; it < 3; ++it) {
            int v = it * 256 + tid;
            async_copy16(wb + (size_t)s * 6144 + v * 8, &Wr[slot][v * 8]);
        }
    };

    // issue 24 fp32 loads for row g (3 cells/thread, wrap-dup past 576).
    auto xload = [&](int g) {
        int cg = g / 3, dhg = g - cg * 3;
        int ha = h - 1 + dhg;
#pragma unroll
        for (int cc = 0; cc < 3; ++cc) {
            int v0 = cc * 256 + tid;
            int v = v0 >= 576 ? v0 - 576 : v0;
            int gg = v / 288, e = v - gg * 288;
            int wa = w0 - 1 + (e >> 4);
            bool ok = ((unsigned)ha < 64u) & ((unsigned)wa < 64u);
            int E = (ha * 64 + wa) * 16 + (e & 15);
            int Ec = ok ? E : 0;       // clamp: loads always in-bounds
            const AS1 float* xp = (const AS1 float*)x +
                (((size_t)(b * 128 + cg * 16 + gg * 8)) << 16) + Ec;
#pragma unroll
            for (int j = 0; j < 8; ++j) XL[cc * 8 + j] = xp[(size_t)j << 16];
        }
    };

    // cvt + ds_write row g from XL (halo rows/cols zeroed by value-select).
    auto xstore = [&](int g) {
        int dhg = g % 3;
        int ha = h - 1 + dhg;
        const bf16 zz = (bf16)0.f;
        const bf16x8 vz = {zz, zz, zz, zz, zz, zz, zz, zz};
#pragma unroll
        for (int cc = 0; cc < 3; ++cc) {
            int v0 = cc * 256 + tid;
            int v = v0 >= 576 ? v0 - 576 : v0;
            int gg = v / 288, e = v - gg * 288;
            int wa = w0 - 1 + (e >> 4);
            bool ok = ((unsigned)ha < 64u) & ((unsigned)wa < 64u);
            bf16x8 vv;
#pragma unroll
            for (int j = 0; j < 8; ++j) vv[j] = (bf16)XL[cc * 8 + j];
            vv = ok ? vv : vz;
            *(bf16x8*)&Xr[dhg][v * 8] = vv;
        }
    };

    f32x16 acc[2][4] = {};

    // epilogue noise first: oldest in vmcnt, retired by the first store-wait
    const size_t ebase = bHW + (size_t)h * 1024 + w0 * 16 + wn * 128;
    float ns[4];
#pragma unroll
    for (int nf = 0; nf < 4; ++nf) ns[nf] = noise[ebase + nf * 32 + l31];
    __builtin_amdgcn_sched_barrier(0);

    // prologue: XL <- row 0, W slab 0
    xload(0);
    wslab(0);
    __builtin_amdgcn_sched_barrier(0);

#define PHASE(c, dh, LIT, DONEXT)                                              \
    {                                                                          \
        if (DONEXT) wslab(3 * (c) + (dh) + 1);                                 \
        xstore(3 * (c) + (dh));                                                \
        if (DONEXT) xload(3 * (c) + (dh) + 1);                                 \
        __builtin_amdgcn_sched_barrier(0);                                     \
        waitv<LIT>();                                                          \
        asm volatile("s_waitcnt lgkmcnt(0)" ::: "memory");                     \
        __builtin_amdgcn_sched_barrier(0);                                     \
        __builtin_amdgcn_s_barrier();                                          \
        _Pragma("unroll")                                                      \
        for (int dw = 0; dw < 3; ++dw) {                                       \
            const bf16* wg =                                                   \
                &Wr[dh][((dw * 2 + lhi) * 128 + wm * 64 + l31) * 8];           \
            bf16x8 a0 = *(const bf16x8*)&wg[0];                                \
            bf16x8 a1 = *(const bf16x8*)&wg[32 * 8];                           \
            const bf16* xb =                                                   \
                &Xr[dh][(lhi * 288 + dw * 16 + wn * 128 + l31) * 8];           \
            bf16x8 b0 = *(const bf16x8*)&xb[0];                                \
            bf16x8 b1 = *(const bf16x8*)&xb[32 * 8];                           \
            bf16x8 b2 = *(const bf16x8*)&xb[64 * 8];                           \
            bf16x8 b3 = *(const bf16x8*)&xb[96 * 8];                           \
            acc[0][0] = __builtin_amdgcn_mfma_f32_32x32x16_bf16(a0, b0, acc[0][0], 0, 0, 0); \
            acc[0][1] = __builtin_amdgcn_mfma_f32_32x32x16_bf16(a0, b1, acc[0][1], 0, 0, 0); \
            acc[0][2] = __builtin_amdgcn_mfma_f32_32x32x16_bf16(a0, b2, acc[0][2], 0, 0, 0); \
            acc[0][3] = __builtin_amdgcn_mfma_f32_32x32x16_bf16(a0, b3, acc[0][3], 0, 0, 0); \
            acc[1][0] = __builtin_amdgcn_mfma_f32_32x32x16_bf16(a1, b0, acc[1][0], 0, 0, 0); \
            acc[1][1] = __builtin_amdgcn_mfma_f32_32x32x16_bf16(a1, b1, acc[1][1], 0, 0, 0); \
            acc[1][2] = __builtin_amdgcn_mfma_f32_32x32x16_bf16(a1, b2, acc[1][2], 0, 0, 0); \
            acc[1][3] = __builtin_amdgcn_mfma_f32_32x32x16_bf16(a1, b3, acc[1][3], 0, 0, 0); \
        }                                                                      \
    }

    for (int c = 0; c < 7; ++c) {
        PHASE(c, 0, 27, true);
        PHASE(c, 1, 27, true);
        PHASE(c, 2, 27, true);
    }
    PHASE(7, 0, 27, true);
    PHASE(7, 1, 27, true);    // p=22: issues W23 + XL23
    PHASE(7, 2, 0, false);    // p=23: store row 23, drain, compute
#undef PHASE

    // epilogue: D col = lane&31 (elem), row = (reg&3)+8*(reg>>2)+4*lhi (co)
#pragma unroll
    for (int fm = 0; fm < 2; ++fm) {
        int cob = wm * 64 + fm * 32 + 4 * lhi;
#pragma unroll
        for (int q = 0; q < 4; ++q) {
            int co4 = cob + 8 * q;
            f32x4 sg = *(const f32x4*)&sig_inv[b * 128 + co4];
            f32x4 np4 = *(const f32x4*)&npar[co4];
            f32x4 bp4 = *(const f32x4*)&bpar[co4];
#pragma unroll
            for (int r = 0; r < 4; ++r) {
                int co = co4 + r;
                float* orow = out + ((size_t)(b * 128 + co) * 64 + h) * 1024 +
                              w0 * 16 + wn * 128;
#pragma unroll
                for (int nf = 0; nf < 4; ++nf) {
                    float v = acc[fm][nf][q * 4 + r];
                    orow[nf * 32 + l31] = v * sg[r] + np4[r] * ns[nf] + bp4[r];
                }
            }
        }
    }
}

// ---------------- fp32 fallback (ws too small) ----------------
__global__ void k_naive(const float* __restrict__ x, const float* __restrict__ weight,
                        const float* __restrict__ s, const float* __restrict__ sig,
                        const float* __restrict__ npar, const float* __restrict__ bpar,
                        const float* __restrict__ noise, float* __restrict__ out) {
    size_t o = (size_t)blockIdx.x * 256 + threadIdx.x;
    int t = o & 15, w = (o >> 4) & 63, h = (o >> 10) & 63;
    int co = (o >> 16) & 127, b = (int)(o >> 23);
    float a = 0.f;
    for (int ci = 0; ci < 128; ++ci) {
        const float* xr = x + (size_t)(b * 128 + ci) * 65536;
        const float* wr = weight + ((size_t)co * 128 + ci) * 9;
        float p = 0.f;
#pragma unroll
        for (int kh = 0; kh < 3; ++kh) {
            int ha = h + kh - 1;
            if ((unsigned)ha >= 64u) continue;
#pragma unroll
            for (int kw = 0; kw < 3; ++kw) {
                int wa = w + kw - 1;
                if ((unsigned)wa >= 64u) continue;
                p += xr[(ha * 64 + wa) * 16 + t] * wr[kh * 3 + kw];
            }
        }
        a += p * s[b * 128 + ci];
    }
    int E = b * 65536 + (h * 64 + w) * 16 + t;
    out[o] = a * sig[b * 128 + co] + npar[co] * noise[E] + bpar[co];
}

// ---------------- host ----------------
extern "C" void kernel_launch(void* const* d_in, const int* in_sizes, int n_in,
                              void* d_out, int out_size, void* d_ws, size_t ws_size,
                              hipStream_t stream) {
    const float* x      = (const float*)d_in[0];
    const float* style  = (const float*)d_in[1];
    const float* noise  = (const float*)d_in[2];
    const float* weight = (const float*)d_in[3];
    const float* sw     = (const float*)d_in[4];
    const float* sb     = (const float*)d_in[5];
    const float* npar   = (const float*)d_in[6];
    const float* bpar   = (const float*)d_in[7];
    float* out = (float*)d_out;

    float* s_buf   = (float*)d_ws;                         // 512 f32
    float* sig_buf = s_buf + 512;                          // 512 f32
    bf16*  wt      = (bf16*)((char*)d_ws + 8192);          // 4 x 294912 B
    const size_t NEED = 8192 + 4 * 294912ull;

    k_style<<<dim3(128), dim3(256), 0, stream>>>(style, sw, sb, s_buf);
    k_sig<<<dim3(128), dim3(256), 0, stream>>>(weight, s_buf, sig_buf);
    if (ws_size >= NEED) {
        k_wt<<<dim3(2304), dim3(256), 0, stream>>>(weight, s_buf, wt);
        conv_main<<<dim3(4, 64, 4), dim3(256), 0, stream>>>(
            x, wt, sig_buf, npar, bpar, noise, out);
    } else {
        k_naive<<<dim3(131072), dim3(256), 0, stream>>>(
            x, weight, s_buf, sig_buf, npar, bpar, noise, out);
    }
}